// Round 1
// 386.587 us; speedup vs baseline: 1.0245x; 1.0245x over previous
//
#include <hip/hip_runtime.h>

#define BB 4
#define TT 2048
#define EE 4096
#define HH 128
#define MM (BB*TT)          // 8192
#define SCALE 0.015625f     // E^-0.5 = 1/64

typedef short short8 __attribute__((ext_vector_type(8)));
typedef float f32x4 __attribute__((ext_vector_type(4)));
typedef unsigned short ushort_t;

__device__ __forceinline__ unsigned short f2bf(float x) {
    unsigned int u = __float_as_uint(x);
    u = (u + 0x7fffu + ((u >> 16) & 1u)) >> 16;   // RNE
    return (unsigned short)u;
}

// ---------------------------------------------------------------------------
// Kernel 1: convert Wq|Wk|Wv -> bf16 [3][128][4096]; Wq pre-scaled by 1/64.
// ---------------------------------------------------------------------------
__global__ __launch_bounds__(256) void wconv(
    const float* __restrict__ Wq, const float* __restrict__ Wk,
    const float* __restrict__ Wv, ushort_t* __restrict__ Wb)
{
    const int gid = blockIdx.x * 256 + threadIdx.x;
    const int which = gid >> 16;
    const int rem = gid & 65535;
    const float* W = (which == 0) ? Wq : (which == 1) ? Wk : Wv;
    const float sc = (which == 0) ? SCALE : 1.0f;
    const float4 f0 = *(const float4*)(W + (size_t)rem * 8);
    const float4 f1 = *(const float4*)(W + (size_t)rem * 8 + 4);
    short8 pk;
    pk[0] = (short)f2bf(f0.x * sc); pk[1] = (short)f2bf(f0.y * sc);
    pk[2] = (short)f2bf(f0.z * sc); pk[3] = (short)f2bf(f0.w * sc);
    pk[4] = (short)f2bf(f1.x * sc); pk[5] = (short)f2bf(f1.y * sc);
    pk[6] = (short)f2bf(f1.z * sc); pk[7] = (short)f2bf(f1.w * sc);
    *(short8*)(Wb + (size_t)which * 524288 + (size_t)rem * 8) = pk;
}

// ---------------------------------------------------------------------------
// Kernel 2 (v2): MFMA projection. Tile 32(M) x 128(N full), K-step 128.
// Grid (256, 3): widx = by (0:q from x, 1:k from pe, 2:v from x).
// A (fp32 input) double-buffered in LDS (convert at write); B (bf16 weights)
// loaded straight from global (L2-resident), register-prefetched 1 step ahead.
// One __syncthreads per K-step; 16 MFMA/wave between barriers.
// q,k stored [m][h] bf16; v stored TRANSPOSED vt[h][m] bf16 (LDS transpose).
// ---------------------------------------------------------------------------
#define PSTR 136   // LDS elems per A row (128 + 8 pad)

#define PACK8(S0, S1, A0, A1, A2, A3) \
    S0[0]=(short)f2bf(A0.x); S0[1]=(short)f2bf(A0.y); S0[2]=(short)f2bf(A0.z); S0[3]=(short)f2bf(A0.w); \
    S0[4]=(short)f2bf(A1.x); S0[5]=(short)f2bf(A1.y); S0[6]=(short)f2bf(A1.z); S0[7]=(short)f2bf(A1.w); \
    S1[0]=(short)f2bf(A2.x); S1[1]=(short)f2bf(A2.y); S1[2]=(short)f2bf(A2.z); S1[3]=(short)f2bf(A2.w); \
    S1[4]=(short)f2bf(A3.x); S1[5]=(short)f2bf(A3.y); S1[6]=(short)f2bf(A3.z); S1[7]=(short)f2bf(A3.w);

#define PROJ_STEP(KB, BUF, PBC, PBN) do { \
    const bool more_ = (KB) + 128 < EE; \
    float4 na0, na1, na2, na3; \
    if (more_) { \
        const float* ap_ = aptr + (KB) + 128; \
        na0 = *(const float4*)ap_;        na1 = *(const float4*)(ap_ + 4); \
        na2 = *(const float4*)(ap_ + 8);  na3 = *(const float4*)(ap_ + 12); \
        _Pragma("unroll") \
        for (int kk = 0; kk < 4; kk++) { \
            PBN[kk]     = *(const short8*)(wp0 + (KB) + 128 + kk * 32); \
            PBN[4 + kk] = *(const short8*)(wp1 + (KB) + 128 + kk * 32); \
        } \
    } \
    _Pragma("unroll") \
    for (int kk = 0; kk < 4; kk++) { \
        const short8 a0_ = *(const short8*)&As[BUF][fr * PSTR + kk * 32 + ko]; \
        const short8 a1_ = *(const short8*)&As[BUF][(16 + fr) * PSTR + kk * 32 + ko]; \
        acc[0][0] = __builtin_amdgcn_mfma_f32_16x16x32_bf16(a0_, PBC[kk],     acc[0][0], 0, 0, 0); \
        acc[0][1] = __builtin_amdgcn_mfma_f32_16x16x32_bf16(a0_, PBC[4 + kk], acc[0][1], 0, 0, 0); \
        acc[1][0] = __builtin_amdgcn_mfma_f32_16x16x32_bf16(a1_, PBC[kk],     acc[1][0], 0, 0, 0); \
        acc[1][1] = __builtin_amdgcn_mfma_f32_16x16x32_bf16(a1_, PBC[4 + kk], acc[1][1], 0, 0, 0); \
    } \
    if (more_) { \
        short8 s0_, s1_; \
        PACK8(s0_, s1_, na0, na1, na2, na3) \
        *(short8*)&As[(BUF) ^ 1][arow * PSTR + acol]     = s0_; \
        *(short8*)&As[(BUF) ^ 1][arow * PSTR + acol + 8] = s1_; \
        __syncthreads(); \
    } \
} while (0)

__global__ __launch_bounds__(256) void proj_mfma(
    const float* __restrict__ x, const float* __restrict__ pe,
    const ushort_t* __restrict__ Wb,
    ushort_t* __restrict__ qo, ushort_t* __restrict__ ko_,
    ushort_t* __restrict__ vto)
{
    const int widx = blockIdx.y;                 // 0:q 1:k 2:v
    const float* in = (widx == 1) ? pe : x;
    const ushort_t* W = Wb + (size_t)widx * 524288;

    const int rb   = blockIdx.x * 32;
    const int tid  = threadIdx.x;
    const int lane = tid & 63, wave = tid >> 6;  // wave = col-group (32 cols each)
    const int fr = lane & 15, quad = lane >> 4, ko = quad * 8;

    __shared__ __align__(16) ushort_t As[2][32 * PSTR];

    f32x4 acc[2][2];
    acc[0][0] = (f32x4){0.f,0.f,0.f,0.f};
    acc[0][1] = (f32x4){0.f,0.f,0.f,0.f};
    acc[1][0] = (f32x4){0.f,0.f,0.f,0.f};
    acc[1][1] = (f32x4){0.f,0.f,0.f,0.f};

    // A staging map: thread -> (row, 16-wide col segment)
    const int arow = tid >> 3, acol = (tid & 7) * 16;
    const float* aptr = in + (size_t)(rb + arow) * EE + acol;

    // B fragment base pointers (per-lane, direct global / L2)
    const ushort_t* wp0 = W + (size_t)(wave * 32 + fr) * EE + ko;
    const ushort_t* wp1 = W + (size_t)(wave * 32 + 16 + fr) * EE + ko;

    short8 pbA[8], pbB[8];

    // ---- prologue: stage A(k=0) to LDS buf0, load B(k=0) frags ----
    {
        float4 a0 = *(const float4*)(aptr);
        float4 a1 = *(const float4*)(aptr + 4);
        float4 a2 = *(const float4*)(aptr + 8);
        float4 a3 = *(const float4*)(aptr + 12);
        #pragma unroll
        for (int kk = 0; kk < 4; kk++) {
            pbA[kk]     = *(const short8*)(wp0 + kk * 32);
            pbA[4 + kk] = *(const short8*)(wp1 + kk * 32);
        }
        short8 s0, s1;
        PACK8(s0, s1, a0, a1, a2, a3)
        *(short8*)&As[0][arow * PSTR + acol]     = s0;
        *(short8*)&As[0][arow * PSTR + acol + 8] = s1;
        __syncthreads();
    }

    // ---- main loop: 32 K-steps, ping-pong register sets (no pb copies) ----
    for (int k0 = 0; k0 < EE; k0 += 256) {
        PROJ_STEP(k0,       0, pbA, pbB);
        PROJ_STEP(k0 + 128, 1, pbB, pbA);
    }

    // ---- epilogue ----
    const int crow = quad * 4;
    if (widx < 2) {
        ushort_t* out = (widx == 0) ? qo : ko_;
        #pragma unroll
        for (int rg = 0; rg < 2; rg++)
            #pragma unroll
            for (int cg = 0; cg < 2; cg++)
                #pragma unroll
                for (int r = 0; r < 4; r++)
                    out[(size_t)(rb + rg * 16 + crow + r) * HH
                        + wave * 32 + cg * 16 + fr] = f2bf(acc[rg][cg][r]);
    } else {
        // LDS transpose: T[h128][m32] stride 40 (80B rows, 16B-aligned)
        __syncthreads();                       // all waves done reading As
        ushort_t* T = (ushort_t*)As;
        #pragma unroll
        for (int rg = 0; rg < 2; rg++)
            #pragma unroll
            for (int cg = 0; cg < 2; cg++)
                #pragma unroll
                for (int r = 0; r < 4; r++)
                    T[(wave * 32 + cg * 16 + fr) * 40 + rg * 16 + crow + r]
                        = f2bf(acc[rg][cg][r]);
        __syncthreads();
        const int col = tid >> 1, m0 = (tid & 1) * 16;
        const short8 v0 = *(short8*)&T[col * 40 + m0];
        const short8 v1 = *(short8*)&T[col * 40 + m0 + 8];
        *(short8*)(vto + (size_t)col * MM + rb + m0)     = v0;
        *(short8*)(vto + (size_t)col * MM + rb + m0 + 8) = v1;
    }
}

// ---------------------------------------------------------------------------
// Kernel 3: MFMA flash attention partials (no-max streaming softmax, split-2).
// Qtile=32, Kchunk=64. Grid (64, 2, BB). bf16 q,k,vt in; fp32 partials out.
// ---------------------------------------------------------------------------
__global__ __launch_bounds__(256) void attn_mfma(
    const ushort_t* __restrict__ qb, const ushort_t* __restrict__ kbf,
    const ushort_t* __restrict__ vtb,
    float* __restrict__ OP, float* __restrict__ LP)
{
    const int b = blockIdx.z;
    const int s = blockIdx.y;
    const int t = 63 - (int)blockIdx.x;       // heavy tiles first
    const int tid  = threadIdx.x;
    const int lane = tid & 63, wave = tid >> 6;
    const int fr = lane & 15, quad = lane >> 4, ko = quad * 8;

    const int q0 = t * 32;
    const int C  = (t + 2) >> 1;              // chunks of 64 keys
    const int cs = (C + 1) >> 1;
    const int c0 = s ? cs : 0;
    const int c1 = s ? C  : cs;

    __shared__ __align__(16) ushort_t Qs[32 * 136];
    __shared__ __align__(16) ushort_t Ks[64 * 136];
    __shared__ __align__(16) ushort_t Vt[128 * 72];
    __shared__ __align__(16) ushort_t Ps[32 * 72];
    __shared__ float lred[2][32];

    // load Q tile (32 rows x 16 segs)
    for (int f = tid; f < 512; f += 256) {
        const int row = f >> 4, sg = f & 15;
        *(short8*)&Qs[row * 136 + sg * 8] =
            *(const short8*)(qb + (size_t)(b * TT + q0 + row) * HH + sg * 8);
    }

    const int rhS = (wave & 1) * 16, cqS = (wave >> 1) * 32;   // S partition
    const int rhO = (wave & 1) * 16, chO = (wave >> 1) * 64;   // O partition

    f32x4 oacc[4];
    #pragma unroll
    for (int i = 0; i < 4; i++) oacc[i] = (f32x4){0.f,0.f,0.f,0.f};
    float lacc[4] = {0.f, 0.f, 0.f, 0.f};

    for (int c = c0; c < c1; c++) {
        const int kb_ = c * 64;
        // stage K (64 x 16 segs)
        for (int f = tid; f < 1024; f += 256) {
            const int row = f >> 4, sg = f & 15;
            *(short8*)&Ks[row * 136 + sg * 8] =
                *(const short8*)(kbf + (size_t)(b * TT + kb_ + row) * HH + sg * 8);
        }
        // stage Vt (128 x 8 segs)
        for (int f = tid; f < 1024; f += 256) {
            const int h = f >> 3, sg = f & 7;
            *(short8*)&Vt[h * 72 + sg * 8] =
                *(const short8*)(vtb + (size_t)h * MM + b * TT + kb_ + sg * 8);
        }
        __syncthreads();

        // ---- QK: S[32x64], this wave: rows rhS..+16, cols cqS..+32 ----
        f32x4 sacc[2];
        sacc[0] = (f32x4){0.f,0.f,0.f,0.f};
        sacc[1] = (f32x4){0.f,0.f,0.f,0.f};
        #pragma unroll
        for (int kk = 0; kk < 128; kk += 32) {
            const short8 af = *(short8*)&Qs[(rhS + fr) * 136 + kk + ko];
            const short8 b0 = *(short8*)&Ks[(cqS + fr) * 136 + kk + ko];
            const short8 b1 = *(short8*)&Ks[(cqS + 16 + fr) * 136 + kk + ko];
            sacc[0] = __builtin_amdgcn_mfma_f32_16x16x32_bf16(af, b0, sacc[0], 0, 0, 0);
            sacc[1] = __builtin_amdgcn_mfma_f32_16x16x32_bf16(af, b1, sacc[1], 0, 0, 0);
        }

        // ---- epilogue: mask + exp -> Ps (bf16), accumulate l ----
        #pragma unroll
        for (int tl = 0; tl < 2; tl++)
            #pragma unroll
            for (int r = 0; r < 4; r++) {
                const int row = rhS + quad * 4 + r;
                const int col = cqS + tl * 16 + fr;
                const float p = ((kb_ + col) <= (q0 + row)) ? __expf(sacc[tl][r]) : 0.f;
                lacc[r] += p;
                Ps[row * 72 + col] = f2bf(p);
            }
        __syncthreads();

        // ---- PV: O[32x128] += P[32x64] * V; wave: rows rhO, cols chO..+64 ----
        #pragma unroll
        for (int ks = 0; ks < 64; ks += 32) {
            const short8 af = *(short8*)&Ps[(rhO + fr) * 72 + ks + ko];
            #pragma unroll
            for (int tl = 0; tl < 4; tl++) {
                const short8 bf_ = *(short8*)&Vt[(chO + tl * 16 + fr) * 72 + ks + ko];
                oacc[tl] = __builtin_amdgcn_mfma_f32_16x16x32_bf16(af, bf_, oacc[tl], 0, 0, 0);
            }
        }
        __syncthreads();
    }

    // ---- l reduction: sum over the 16 fr-lanes, combine col-halves ----
    #pragma unroll
    for (int r = 0; r < 4; r++) {
        float v = lacc[r];
        #pragma unroll
        for (int m = 1; m < 16; m <<= 1) v += __shfl_xor(v, m);
        lacc[r] = v;
    }
    if (fr == 0) {
        #pragma unroll
        for (int r = 0; r < 4; r++)
            lred[wave >> 1][rhS + quad * 4 + r] = lacc[r];
    }
    __syncthreads();
    const int pbase = ((b * 64 + t) * 2 + s);
    if (tid < 32) LP[(size_t)pbase * 32 + tid] = lred[0][tid] + lred[1][tid];

    // ---- write O partial ----
    #pragma unroll
    for (int tl = 0; tl < 4; tl++)
        #pragma unroll
        for (int r = 0; r < 4; r++) {
            const int row = rhO + quad * 4 + r;
            const int col = chO + tl * 16 + fr;
            OP[(size_t)pbase * 4096 + row * 128 + col] = oacc[tl][r];
        }
}

// ---------------------------------------------------------------------------
// Kernel 4: combine: out = (O0+O1)/(l0+l1). 262144 float4.
// ---------------------------------------------------------------------------
__global__ __launch_bounds__(256) void combine(
    const float* __restrict__ OP, const float* __restrict__ LP,
    float* __restrict__ out)
{
    const int gid = blockIdx.x * 256 + threadIdx.x;
    const int b = gid >> 16;
    const int rem = gid & 65535;
    const int qrow = rem >> 5, h4 = rem & 31;
    const int t = qrow >> 5, r = qrow & 31;
    const int base = (b * 64 + t) * 2;
    const float l = LP[(size_t)base * 32 + r] + LP[(size_t)(base + 1) * 32 + r];
    const float inv = 1.f / l;
    const float4 a = ((const float4*)OP)[(size_t)base * 1024 + r * 32 + h4];
    const float4 c = ((const float4*)OP)[(size_t)(base + 1) * 1024 + r * 32 + h4];
    float4 res;
    res.x = (a.x + c.x) * inv; res.y = (a.y + c.y) * inv;
    res.z = (a.z + c.z) * inv; res.w = (a.w + c.w) * inv;
    ((float4*)out)[gid] = res;
}

// ---------------------------------------------------------------------------
extern "C" void kernel_launch(void* const* d_in, const int* in_sizes, int n_in,
                              void* d_out, int out_size, void* d_ws, size_t ws_size,
                              hipStream_t stream) {
    const float* x  = (const float*)d_in[0];
    const float* pe = (const float*)d_in[1];
    const float* Wq = (const float*)d_in[2];
    const float* Wk = (const float*)d_in[3];
    const float* Wv = (const float*)d_in[4];
    float* out = (float*)d_out;

    ushort_t* qb  = (ushort_t*)d_ws;                 // [MM][HH] bf16
    ushort_t* kbf = qb  + (size_t)MM * HH;           // [MM][HH] bf16
    ushort_t* vtb = kbf + (size_t)MM * HH;           // [HH][MM] bf16 (transposed)
    ushort_t* Wb  = vtb + (size_t)MM * HH;           // [3][128][4096] bf16
    float* OP = (float*)(Wb + (size_t)3 * 128 * 4096);  // [512][4096] f32
    float* LP = OP + (size_t)512 * 4096;             // [512][32] f32

    wconv    <<<768, 256, 0, stream>>>(Wq, Wk, Wv, Wb);
    proj_mfma<<<dim3(256, 3), 256, 0, stream>>>(x, pe, Wb, qb, kbf, vtb);
    attn_mfma<<<dim3(64, 2, BB), 256, 0, stream>>>(qb, kbf, vtb, OP, LP);
    combine  <<<1024, 256, 0, stream>>>(OP, LP, out);
}